// Round 1
// baseline (207.990 us; speedup 1.0000x reference)
//
#include <hip/hip_runtime.h>

#define NEG (-1e9f)
constexpr int NCLS  = 21;
constexpr int NBOX  = 8732;
constexpr int MAXOUT = 5;
constexpr float IOU_THR  = 0.5f;
constexpr float CONF_THR = 0.5f;

// ---------------------------------------------------------------------------
// Phase 1: per-box decode + softmax max/argmax.  One thread per (b,n) box.
//   boxes[i]  = decoded, clipped corner box (y1,x1,y2,x2)
//   scores[i] = max softmax prob, or NEG if argmax class == 0 (background)
//   cls[i]    = argmax class as float
// ---------------------------------------------------------------------------
__global__ void decode_kernel(const float* __restrict__ logits,
                              const float* __restrict__ dbox,
                              float4* __restrict__ boxes,
                              float*  __restrict__ scores,
                              float*  __restrict__ cls,
                              int BN) {
    int i = blockIdx.x * blockDim.x + threadIdx.x;
    if (i >= BN) return;
    int n = i % NBOX;
    const float* L = logits + (long long)i * (4 + NCLS);

    // decode (matches reference _decode exactly: div-by-2 is exact in fp32)
    float d0 = dbox[n * 4 + 0], d1 = dbox[n * 4 + 1];
    float d2 = dbox[n * 4 + 2], d3 = dbox[n * 4 + 3];
    float cy = (d2 + d0) * 0.5f;
    float cx = (d3 + d1) * 0.5f;
    float h  = d2 - d0;
    float w  = d3 - d1;
    float l0 = L[0], l1 = L[1], l2 = L[2], l3 = L[3];
    float ncy = l0 * h + cy;
    float ncx = l1 * w + cx;
    float nh  = expf(l2) * h;
    float nw  = expf(l3) * w;
    float y1 = fminf(fmaxf(ncy - nh * 0.5f, 0.f), 1.f);
    float x1 = fminf(fmaxf(ncx - nw * 0.5f, 0.f), 1.f);
    float y2 = fminf(fmaxf(ncy + nh * 0.5f, 0.f), 1.f);
    float x2 = fminf(fmaxf(ncx + nw * 0.5f, 0.f), 1.f);
    boxes[i] = make_float4(y1, x1, y2, x2);

    // softmax: argmax(probs) == argmax(logits) (first index on ties);
    // max(probs) == exp(0)/sum == 1/sum  (same rounding as reference's divide)
    float m = L[4];
    int am = 0;
#pragma unroll
    for (int j = 1; j < NCLS; j++) {
        float x = L[4 + j];
        if (x > m) { m = x; am = j; }   // strict > keeps first occurrence
    }
    float sum = 0.f;
#pragma unroll
    for (int j = 0; j < NCLS; j++) sum += expf(L[4 + j] - m);
    float score = 1.0f / sum;

    scores[i] = (am != 0) ? score : NEG;
    cls[i]    = (float)am;
}

// ---------------------------------------------------------------------------
// Phase 2: NMS, one block (256 threads) per batch element.
// Scores live in LDS; 5 iterations of argmax (first-index tie-break, matching
// jnp.argmax) + IoU suppression (strict >0.5, eps 1e-12, includes self).
// ---------------------------------------------------------------------------
__global__ __launch_bounds__(256) void nms_kernel(const float4* __restrict__ boxes,
                                                  const float*  __restrict__ scores,
                                                  const float*  __restrict__ cls,
                                                  float* __restrict__ out) {
    const int b = blockIdx.x;
    const int t = threadIdx.x;
    __shared__ float s_sc[NBOX];
    __shared__ float r_val[256];
    __shared__ int   r_idx[256];
    __shared__ float sel_box[4];

    const float4* bb = boxes  + (long long)b * NBOX;
    const float*  ss = scores + (long long)b * NBOX;

    for (int i = t; i < NBOX; i += 256) s_sc[i] = ss[i];
    __syncthreads();

    for (int k = 0; k < MAXOUT; k++) {
        // --- block argmax with first-index tie-break ---
        float bv = -INFINITY;
        int   bi = NBOX;
        for (int i = t; i < NBOX; i += 256) {
            float v = s_sc[i];
            if (v > bv) { bv = v; bi = i; }   // ascending i => first index kept
        }
        r_val[t] = bv; r_idx[t] = bi;
        __syncthreads();
        for (int off = 128; off > 0; off >>= 1) {
            if (t < off) {
                float v2 = r_val[t + off]; int i2 = r_idx[t + off];
                if (v2 > r_val[t] || (v2 == r_val[t] && i2 < r_idx[t])) {
                    r_val[t] = v2; r_idx[t] = i2;
                }
            }
            __syncthreads();
        }
        int   sel = r_idx[0];
        float sc  = r_val[0];

        if (t == 0) {
            float4 bx = bb[sel];
            sel_box[0] = bx.x; sel_box[1] = bx.y;
            sel_box[2] = bx.z; sel_box[3] = bx.w;
            float* o = out + ((long long)b * MAXOUT + k) * 6;
            bool valid = sc > CONF_THR;
            if (valid) {
                o[0] = bx.x; o[1] = bx.y; o[2] = bx.z; o[3] = bx.w;
                o[4] = cls[(long long)b * NBOX + sel];
                o[5] = sc;
            } else {
                o[0] = 0.f; o[1] = 0.f; o[2] = 0.f;
                o[3] = 0.f; o[4] = 0.f; o[5] = 0.f;
            }
        }
        __syncthreads();

        // --- IoU suppression (reference formula, includes self) ---
        float by1 = sel_box[0], bx1 = sel_box[1];
        float by2 = sel_box[2], bx2 = sel_box[3];
        float a1 = (by2 - by1) * (bx2 - bx1);
        for (int i = t; i < NBOX; i += 256) {
            float4 c = bb[i];
            float tly = fmaxf(by1, c.x);
            float tlx = fmaxf(bx1, c.y);
            float bry = fminf(by2, c.z);
            float brx = fminf(bx2, c.w);
            float wh0 = fmaxf(bry - tly, 0.f);
            float wh1 = fmaxf(brx - tlx, 0.f);
            float inter = wh0 * wh1;
            float a2 = (c.z - c.x) * (c.w - c.y);
            float iou = inter / (a1 + a2 - inter + 1e-12f);
            if (iou > IOU_THR) s_sc[i] = NEG;
        }
        __syncthreads();
    }
}

extern "C" void kernel_launch(void* const* d_in, const int* in_sizes, int n_in,
                              void* d_out, int out_size, void* d_ws, size_t ws_size,
                              hipStream_t stream) {
    const float* logits = (const float*)d_in[0];
    const float* dbox   = (const float*)d_in[1];
    float* out          = (float*)d_out;

    const int N  = in_sizes[1] / 4;           // 8732
    const int B  = in_sizes[0] / (N * 25);    // 128
    const int BN = B * N;

    // workspace layout: boxes (float4) | scores (float) | cls (float)
    float4* ws_boxes  = (float4*)d_ws;
    float*  ws_scores = (float*)((char*)d_ws + (size_t)BN * sizeof(float4));
    float*  ws_cls    = ws_scores + BN;

    decode_kernel<<<(BN + 255) / 256, 256, 0, stream>>>(
        logits, dbox, ws_boxes, ws_scores, ws_cls, BN);
    nms_kernel<<<B, 256, 0, stream>>>(ws_boxes, ws_scores, ws_cls, out);
}

// Round 2
// 206.987 us; speedup vs baseline: 1.0048x; 1.0048x over previous
//
#include <hip/hip_runtime.h>

#define NEG (-1e9f)
constexpr int NCLS   = 21;
constexpr int NBOX   = 8732;
constexpr int MAXOUT = 5;
constexpr int CAP    = NBOX;          // worst-case candidates per batch
constexpr float IOU_THR  = 0.5f;
constexpr float CONF_THR = 0.5f;

// ---------------------------------------------------------------------------
// Phase 1: decode + softmax max/argmax + candidate compaction.
// Only boxes with (argmax class != 0 && score > CONF_THR) can ever appear in
// the output (see analysis: a selection with score <= 0.5 makes that slot and
// all later slots zeros, and its suppression can no longer matter).
// Candidate record: 2x float4 = {y1,x1,y2,x2}, {score, cls, orig_idx, 0}.
// Logits staged through LDS for coalesced global loads (stride-25 LDS reads
// are odd-stride -> bank-conflict-free).
// ---------------------------------------------------------------------------
__global__ __launch_bounds__(256) void decode_kernel(
        const float* __restrict__ logits,
        const float* __restrict__ dbox,
        float4* __restrict__ cand,
        int* __restrict__ cnt,
        int BN) {
    __shared__ float sl[256 * 25];          // 25.6 KB
    const int t = threadIdx.x;
    const long long baseF = (long long)blockIdx.x * (256 * 25);
    const long long totalF = (long long)BN * 25;

    // coalesced float4 staging (6400 floats = 1600 float4; block base is
    // 25600 B -> 16B-aligned)
    const float4* gl = (const float4*)(logits + baseF);
    float4* sl4 = (float4*)sl;
    for (int j = t; j < 1600; j += 256) {
        if (baseF + (long long)j * 4 + 3 < totalF) sl4[j] = gl[j];
    }
    __syncthreads();

    const int i = blockIdx.x * 256 + t;
    if (i >= BN) return;
    const float* L = sl + t * 25;
    const int n = i % NBOX;
    const int b = i / NBOX;

    // decode (identical expression order to reference)
    float d0 = dbox[n * 4 + 0], d1 = dbox[n * 4 + 1];
    float d2 = dbox[n * 4 + 2], d3 = dbox[n * 4 + 3];
    float cy = (d2 + d0) * 0.5f;
    float cx = (d3 + d1) * 0.5f;
    float h  = d2 - d0;
    float w  = d3 - d1;
    float ncy = L[0] * h + cy;
    float ncx = L[1] * w + cx;
    float nh  = expf(L[2]) * h;
    float nw  = expf(L[3]) * w;
    float y1 = fminf(fmaxf(ncy - nh * 0.5f, 0.f), 1.f);
    float x1 = fminf(fmaxf(ncx - nw * 0.5f, 0.f), 1.f);
    float y2 = fminf(fmaxf(ncy + nh * 0.5f, 0.f), 1.f);
    float x2 = fminf(fmaxf(ncx + nw * 0.5f, 0.f), 1.f);

    // softmax max/argmax: argmax(probs)==argmax(logits), first index on ties;
    // max prob = 1/sum(exp(x - max)) with same accumulation order as reference
    float m = L[4];
    int am = 0;
#pragma unroll
    for (int j = 1; j < NCLS; j++) {
        float x = L[4 + j];
        if (x > m) { m = x; am = j; }
    }
    float sum = 0.f;
#pragma unroll
    for (int j = 0; j < NCLS; j++) sum += expf(L[4 + j] - m);
    float score = 1.0f / sum;

    if (am != 0 && score > CONF_THR) {
        int p = atomicAdd(&cnt[b], 1);
        if (p < CAP) {
            float4* c = cand + ((long long)b * CAP + p) * 2;
            c[0] = make_float4(y1, x1, y2, x2);
            c[1] = make_float4(score, (float)am, (float)n, 0.f);
        }
    }
}

// ---------------------------------------------------------------------------
// Phase 2: exact NMS over the candidate set. One block per batch element.
// Selection order: (score desc, original index asc) == jnp.argmax semantics.
// ---------------------------------------------------------------------------
__global__ __launch_bounds__(256) void nms_kernel(
        const float4* __restrict__ cand,
        const int* __restrict__ cnt,
        float* __restrict__ out) {
    const int b = blockIdx.x;
    const int t = threadIdx.x;
    __shared__ float s_sc[CAP];
    __shared__ float s_id[CAP];
    __shared__ float r_v[256];
    __shared__ float r_oid[256];
    __shared__ int   r_i[256];
    __shared__ float4 selbox_sh;

    const int M = min(cnt[b], CAP);
    const float4* cb = cand + (long long)b * CAP * 2;

    for (int i = t; i < M; i += 256) {
        float4 mrec = cb[i * 2 + 1];
        s_sc[i] = mrec.x;
        s_id[i] = mrec.z;
    }
    __syncthreads();

    for (int k = 0; k < MAXOUT; k++) {
        // block argmax, lexicographic (score desc, orig idx asc)
        float bv = -INFINITY, boid = 3.0e38f;
        int bi = -1;
        for (int i = t; i < M; i += 256) {
            float v = s_sc[i], oid = s_id[i];
            if (v > bv || (v == bv && oid < boid)) { bv = v; boid = oid; bi = i; }
        }
        r_v[t] = bv; r_oid[t] = boid; r_i[t] = bi;
        __syncthreads();
        for (int off = 128; off > 0; off >>= 1) {
            if (t < off) {
                float v2 = r_v[t + off];
                if (v2 > r_v[t] || (v2 == r_v[t] && r_oid[t + off] < r_oid[t])) {
                    r_v[t] = v2; r_oid[t] = r_oid[t + off]; r_i[t] = r_i[t + off];
                }
            }
            __syncthreads();
        }
        const int   sel = r_i[0];
        const float sc  = r_v[0];
        const bool valid = (sel >= 0) && (sc > CONF_THR);

        if (t == 0) {
            float* o = out + ((long long)b * MAXOUT + k) * 6;
            if (valid) {
                float4 bx = cb[sel * 2];
                float4 mm = cb[sel * 2 + 1];
                selbox_sh = bx;
                o[0] = bx.x; o[1] = bx.y; o[2] = bx.z; o[3] = bx.w;
                o[4] = mm.y; o[5] = sc;
            } else {
                o[0] = 0.f; o[1] = 0.f; o[2] = 0.f;
                o[3] = 0.f; o[4] = 0.f; o[5] = 0.f;
            }
        }
        __syncthreads();
        if (!valid) continue;  // block-uniform; later slots all zeros anyway

        // IoU suppression over candidates (reference formula, includes self)
        float4 sb = selbox_sh;
        float a1 = (sb.z - sb.x) * (sb.w - sb.y);
        for (int i = t; i < M; i += 256) {
            float4 c = cb[i * 2];
            float tly = fmaxf(sb.x, c.x);
            float tlx = fmaxf(sb.y, c.y);
            float bry = fminf(sb.z, c.z);
            float brx = fminf(sb.w, c.w);
            float wh0 = fmaxf(bry - tly, 0.f);
            float wh1 = fmaxf(brx - tlx, 0.f);
            float inter = wh0 * wh1;
            float a2 = (c.z - c.x) * (c.w - c.y);
            float iou = inter / (a1 + a2 - inter + 1e-12f);
            if (iou > IOU_THR) s_sc[i] = NEG;
        }
        __syncthreads();
    }
}

extern "C" void kernel_launch(void* const* d_in, const int* in_sizes, int n_in,
                              void* d_out, int out_size, void* d_ws, size_t ws_size,
                              hipStream_t stream) {
    const float* logits = (const float*)d_in[0];
    const float* dbox   = (const float*)d_in[1];
    float* out          = (float*)d_out;

    const int N  = in_sizes[1] / 4;           // 8732
    const int B  = in_sizes[0] / (N * 25);    // 128
    const int BN = B * N;

    // ws layout: [cnt: B ints][pad to 16B][cand: B*CAP*2 float4]
    int* cnt = (int*)d_ws;
    float4* cand = (float4*)((char*)d_ws + (((size_t)B * sizeof(int) + 15) & ~(size_t)15));

    hipMemsetAsync(cnt, 0, (size_t)B * sizeof(int), stream);
    decode_kernel<<<(BN + 255) / 256, 256, 0, stream>>>(logits, dbox, cand, cnt, BN);
    nms_kernel<<<B, 256, 0, stream>>>(cand, cnt, out);
}

// Round 3
// 194.414 us; speedup vs baseline: 1.0698x; 1.0647x over previous
//
#include <hip/hip_runtime.h>

#define NEG (-1e9f)
constexpr int NCLS   = 21;
constexpr int NBOX   = 8732;
constexpr int MAXOUT = 5;
constexpr int CAP    = NBOX;          // worst-case candidates per batch
constexpr float IOU_THR  = 0.5f;
constexpr float CONF_THR = 0.5f;

// ---------------------------------------------------------------------------
// Phase 1: decode + softmax max/argmax + candidate compaction.
// 4 consecutive boxes per thread: 4*25 = 100 floats = 25 aligned float4 loads
// (g multiple of 4 -> byte offset g*100 is a multiple of 400 = 25*16, so the
// float4 pointer is 16B-aligned). No LDS, no barriers; each wave streams
// 25.6 KB contiguous with 25 outstanding dwordx4 loads, and 4 independent
// exp chains per thread provide the ILP the one-box-per-thread version lacked.
// Arithmetic per box is identical to the reference (bit-exact).
// ---------------------------------------------------------------------------
__device__ __forceinline__ void process_box(
        const float* __restrict__ v,   // 25 floats for this box (in registers)
        int idx,                        // global box index b*NBOX+n
        const float* __restrict__ dbox,
        float4* __restrict__ cand,
        int* __restrict__ cnt) {
    const int n = idx % NBOX;
    const int b = idx / NBOX;

    // decode (identical expression order to reference)
    float d0 = dbox[n * 4 + 0], d1 = dbox[n * 4 + 1];
    float d2 = dbox[n * 4 + 2], d3 = dbox[n * 4 + 3];
    float cy = (d2 + d0) * 0.5f;
    float cx = (d3 + d1) * 0.5f;
    float h  = d2 - d0;
    float w  = d3 - d1;
    float ncy = v[0] * h + cy;
    float ncx = v[1] * w + cx;
    float nh  = expf(v[2]) * h;
    float nw  = expf(v[3]) * w;
    float y1 = fminf(fmaxf(ncy - nh * 0.5f, 0.f), 1.f);
    float x1 = fminf(fmaxf(ncx - nw * 0.5f, 0.f), 1.f);
    float y2 = fminf(fmaxf(ncy + nh * 0.5f, 0.f), 1.f);
    float x2 = fminf(fmaxf(ncx + nw * 0.5f, 0.f), 1.f);

    // argmax(probs)==argmax(logits), first index on ties;
    // max prob = 1/sum(exp(x-max)), same accumulation order as reference
    float m = v[4];
    int am = 0;
#pragma unroll
    for (int j = 1; j < NCLS; j++) {
        float x = v[4 + j];
        if (x > m) { m = x; am = j; }
    }
    float sum = 0.f;
#pragma unroll
    for (int j = 0; j < NCLS; j++) sum += expf(v[4 + j] - m);
    float score = 1.0f / sum;

    if (am != 0 && score > CONF_THR) {
        int p = atomicAdd(&cnt[b], 1);
        if (p < CAP) {
            float4* c = cand + ((long long)b * CAP + p) * 2;
            c[0] = make_float4(y1, x1, y2, x2);
            c[1] = make_float4(score, (float)am, (float)n, 0.f);
        }
    }
}

__global__ __launch_bounds__(256) void decode_kernel(
        const float* __restrict__ logits,
        const float* __restrict__ dbox,
        float4* __restrict__ cand,
        int* __restrict__ cnt,
        int BN) {
    const int g = (blockIdx.x * 256 + threadIdx.x) * 4;
    if (g >= BN) return;

    if (g + 3 < BN) {
        // fast path: 25 aligned float4 loads covering 4 boxes
        const float4* f4 = (const float4*)(logits + (long long)g * 25);
        float v[100];
#pragma unroll
        for (int k = 0; k < 25; k++) {
            float4 r = f4[k];
            v[4 * k + 0] = r.x; v[4 * k + 1] = r.y;
            v[4 * k + 2] = r.z; v[4 * k + 3] = r.w;
        }
#pragma unroll
        for (int j = 0; j < 4; j++)
            process_box(v + 25 * j, g + j, dbox, cand, cnt);
    } else {
        // tail (only hit if BN % 4 != 0): scalar per-box loads
        for (int j = 0; j < 4 && g + j < BN; j++) {
            const float* L = logits + (long long)(g + j) * 25;
            float v[25];
#pragma unroll
            for (int k = 0; k < 25; k++) v[k] = L[k];
            process_box(v, g + j, dbox, cand, cnt);
        }
    }
}

// ---------------------------------------------------------------------------
// Phase 2: exact NMS over the candidate set. One block per batch element.
// Selection order: (score desc, original index asc) == jnp.argmax semantics.
// ---------------------------------------------------------------------------
__global__ __launch_bounds__(256) void nms_kernel(
        const float4* __restrict__ cand,
        const int* __restrict__ cnt,
        float* __restrict__ out) {
    const int b = blockIdx.x;
    const int t = threadIdx.x;
    __shared__ float s_sc[CAP];
    __shared__ float s_id[CAP];
    __shared__ float r_v[256];
    __shared__ float r_oid[256];
    __shared__ int   r_i[256];
    __shared__ float4 selbox_sh;

    const int M = min(cnt[b], CAP);
    const float4* cb = cand + (long long)b * CAP * 2;

    for (int i = t; i < M; i += 256) {
        float4 mrec = cb[i * 2 + 1];
        s_sc[i] = mrec.x;
        s_id[i] = mrec.z;
    }
    __syncthreads();

    for (int k = 0; k < MAXOUT; k++) {
        // block argmax, lexicographic (score desc, orig idx asc)
        float bv = -INFINITY, boid = 3.0e38f;
        int bi = -1;
        for (int i = t; i < M; i += 256) {
            float v = s_sc[i], oid = s_id[i];
            if (v > bv || (v == bv && oid < boid)) { bv = v; boid = oid; bi = i; }
        }
        r_v[t] = bv; r_oid[t] = boid; r_i[t] = bi;
        __syncthreads();
        for (int off = 128; off > 0; off >>= 1) {
            if (t < off) {
                float v2 = r_v[t + off];
                if (v2 > r_v[t] || (v2 == r_v[t] && r_oid[t + off] < r_oid[t])) {
                    r_v[t] = v2; r_oid[t] = r_oid[t + off]; r_i[t] = r_i[t + off];
                }
            }
            __syncthreads();
        }
        const int   sel = r_i[0];
        const float sc  = r_v[0];
        const bool valid = (sel >= 0) && (sc > CONF_THR);

        if (t == 0) {
            float* o = out + ((long long)b * MAXOUT + k) * 6;
            if (valid) {
                float4 bx = cb[sel * 2];
                float4 mm = cb[sel * 2 + 1];
                selbox_sh = bx;
                o[0] = bx.x; o[1] = bx.y; o[2] = bx.z; o[3] = bx.w;
                o[4] = mm.y; o[5] = sc;
            } else {
                o[0] = 0.f; o[1] = 0.f; o[2] = 0.f;
                o[3] = 0.f; o[4] = 0.f; o[5] = 0.f;
            }
        }
        __syncthreads();
        if (!valid) continue;  // block-uniform; later slots all zeros anyway

        // IoU suppression over candidates (reference formula, includes self)
        float4 sb = selbox_sh;
        float a1 = (sb.z - sb.x) * (sb.w - sb.y);
        for (int i = t; i < M; i += 256) {
            float4 c = cb[i * 2];
            float tly = fmaxf(sb.x, c.x);
            float tlx = fmaxf(sb.y, c.y);
            float bry = fminf(sb.z, c.z);
            float brx = fminf(sb.w, c.w);
            float wh0 = fmaxf(bry - tly, 0.f);
            float wh1 = fmaxf(brx - tlx, 0.f);
            float inter = wh0 * wh1;
            float a2 = (c.z - c.x) * (c.w - c.y);
            float iou = inter / (a1 + a2 - inter + 1e-12f);
            if (iou > IOU_THR) s_sc[i] = NEG;
        }
        __syncthreads();
    }
}

extern "C" void kernel_launch(void* const* d_in, const int* in_sizes, int n_in,
                              void* d_out, int out_size, void* d_ws, size_t ws_size,
                              hipStream_t stream) {
    const float* logits = (const float*)d_in[0];
    const float* dbox   = (const float*)d_in[1];
    float* out          = (float*)d_out;

    const int N  = in_sizes[1] / 4;           // 8732
    const int B  = in_sizes[0] / (N * 25);    // 128
    const int BN = B * N;

    // ws layout: [cnt: B ints][pad to 16B][cand: B*CAP*2 float4]
    int* cnt = (int*)d_ws;
    float4* cand = (float4*)((char*)d_ws + (((size_t)B * sizeof(int) + 15) & ~(size_t)15));

    hipMemsetAsync(cnt, 0, (size_t)B * sizeof(int), stream);
    const int nthreads = (BN + 3) / 4;
    decode_kernel<<<(nthreads + 255) / 256, 256, 0, stream>>>(logits, dbox, cand, cnt, BN);
    nms_kernel<<<B, 256, 0, stream>>>(cand, cnt, out);
}